// Round 6
// baseline (692.321 us; speedup 1.0000x reference)
//
#include <hip/hip_runtime.h>
#include <math.h>

#define EPS     1e-6f
#define LROW    8192
#define NLAYER  10
#define NT      512            // 8 waves / block, one row per block

// LDS: s and ratio each as two half-arrays (hi f16, lo f16 scaled by 2^11).
// elem e -> byte swz(2*(e+16)) inside a half-array; 16-elem zero guards both ends.
#define HBUF    16448          // (16 + 8192 + 16) * 2 bytes
#define SCALE_F   2048.0f
#define INV_SCALE 4.8828125e-4f   // 2^-11

typedef _Float16 half8  __attribute__((ext_vector_type(8)));
typedef __fp16   fp16x2 __attribute__((ext_vector_type(2)));
typedef float    f32x16 __attribute__((ext_vector_type(16)));

union H8U { uint4 u; half8 h; };
union H2U { fp16x2 h; unsigned int u; };

__device__ __forceinline__ half8 ldfrag(const char* p) {
    H8U w; w.u = *(const uint4*)(p); return w.h;
}

// XOR-swizzle: relocate each 16B slot within its 128B line by (line&7).
// For the 32x32 fragment pattern (64 distinct blocks at 64j+16h) this makes
// every 8-lane phase hit all 8 bank-groups exactly once (verified by hand).
__device__ __forceinline__ int swz(int a) { return a ^ ((a >> 3) & 0x70); }

struct HL { _Float16 h, l; };
__device__ __forceinline__ HL fsplit(float v) {
    HL r;
    r.h = (_Float16)v;
    r.l = (_Float16)((v - (float)r.h) * SCALE_F);
    return r;
}

__device__ __forceinline__ float sgpr_f(float v) {
    return __int_as_float(__builtin_amdgcn_readfirstlane(__float_as_int(v)));
}

__global__ __launch_bounds__(NT, 4) void drl_kernel(
    const float* __restrict__ m,
    const float* __restrict__ psf,
    const float* __restrict__ alpha,
    float* __restrict__ out)
{
    __shared__ __align__(16) char lds[4 * HBUF + 384];
    char* SBh = lds;                 // s hi
    char* SBl = lds + HBUF;          // s lo (scaled)
    char* RBh = lds + 2 * HBUF;      // ratio hi
    char* RBl = lds + 3 * HBUF;      // ratio lo (scaled)
    float* wl2 = (float*)(lds + 4 * HBUF);   // 96-entry zero-padded taps

    const int t    = threadIdx.x;
    const int lane = t & 63;
    const int wid  = t >> 6;         // wave id 0..7
    const int aj   = lane & 31;      // A row / B col / C col
    const int h    = lane >> 5;      // k-half select
    const int col  = 32 * wid + aj;  // this lane's output group (0..255)
    const int row  = blockIdx.x;
    const float* mrow = m + (size_t)row * LROW;
    float*       orow = out + (size_t)row * LROW;

    // bulk-zero all four half-arrays (covers guards and lo arrays) + taps
    {
        const uint4 z4 = make_uint4(0u, 0u, 0u, 0u);
        uint4* z = (uint4*)lds;
#pragma unroll
        for (int k = 0; k < 9; ++k) {
            int i = t + NT * k;
            if (i < 4112) z[i] = z4;          // 4*16448/16 = 4112 blocks
        }
        if (t < 96) wl2[t] = (t >= 32 && t <= 62) ? psf[t - 32] : 0.0f;
    }
    __syncthreads();

    // s interior hi = 0.5h (16 elems per thread, two swizzled 16B stores)
    {
        const uint4 p5 = make_uint4(0x38003800u, 0x38003800u, 0x38003800u, 0x38003800u);
        int a0 = swz(32 * t + 32);
        *(uint4*)(SBh + a0) = p5;
        int a1 = swz(32 * t + 48);
        *(uint4*)(SBh + a1) = p5;
    }
    __syncthreads();

    // A-fragments for 32x32x16 f16 MFMA, 4 K-chunks, hi/lo split.
    // A_c[i][kk] = psf[16c + kk - i - 1] (zero-padded), i = aj, kk = 8h + j.
    // psf is bitwise symmetric => same fragments serve both convolutions.
    half8 hA[4], lA[4];
#pragma unroll
    for (int c = 0; c < 4; ++c) {
#pragma unroll
        for (int j = 0; j < 8; ++j) {
            HL w = fsplit(wl2[16 * c + 8 * h + j - aj + 31]);
            hA[c][j] = w.h; lA[c][j] = w.l;
        }
    }

    // swizzled byte offsets (per K-chunk reads, per reg-quad writes)
    int rb[4], wb[4];
#pragma unroll
    for (int c = 0; c < 4; ++c) {
        rb[c] = swz(64 * col + 32 * c + 16 * h);       // B frag: elem 32col-16+16c+8h
        wb[c] = swz(64 * col + 16 * c + 8 * h + 32);   // C quad: elem 32col+8c+4h
    }

    // x in C layout: reg r -> elem 32col + 8*(r>>2) + 4h + (r&3)
    float xr[16];
#pragma unroll
    for (int q = 0; q < 4; ++q) {
        float4 v = *(const float4*)(mrow + 32 * col + 8 * q + 4 * h);
        xr[4*q+0] = v.x; xr[4*q+1] = v.y; xr[4*q+2] = v.z; xr[4*q+3] = v.w;
    }

    float sreg[16];
#pragma unroll
    for (int i = 0; i < 16; ++i) sreg[i] = 0.5f;

#pragma unroll 1
    for (int layer = 0; layer < NLAYER; ++layer) {
        const float av = sgpr_f(alpha[layer]);

        // ---- conv1: s (SB) -> ratio (RB) ----
        {
            f32x16 H, L1, L2;
#pragma unroll
            for (int i = 0; i < 16; ++i) { H[i] = EPS; L1[i] = 0.0f; L2[i] = 0.0f; }
#pragma unroll
            for (int c = 0; c < 4; ++c) {
                half8 hB = ldfrag(SBh + rb[c]);
                half8 lB = ldfrag(SBl + rb[c]);
                H  = __builtin_amdgcn_mfma_f32_32x32x16_f16(hA[c], hB, H,  0, 0, 0);
                L1 = __builtin_amdgcn_mfma_f32_32x32x16_f16(lA[c], hB, L1, 0, 0, 0);
                L2 = __builtin_amdgcn_mfma_f32_32x32x16_f16(hA[c], lB, L2, 0, 0, 0);
            }
#pragma unroll
            for (int q = 0; q < 4; ++q) {
                float a0 = fmaf(L1[4*q+0] + L2[4*q+0], INV_SCALE, H[4*q+0]);
                float a1 = fmaf(L1[4*q+1] + L2[4*q+1], INV_SCALE, H[4*q+1]);
                float a2 = fmaf(L1[4*q+2] + L2[4*q+2], INV_SCALE, H[4*q+2]);
                float a3 = fmaf(L1[4*q+3] + L2[4*q+3], INV_SCALE, H[4*q+3]);
                float r0 = xr[4*q+0] * __builtin_amdgcn_rcpf(a0);
                float r1 = xr[4*q+1] * __builtin_amdgcn_rcpf(a1);
                float r2 = xr[4*q+2] * __builtin_amdgcn_rcpf(a2);
                float r3 = xr[4*q+3] * __builtin_amdgcn_rcpf(a3);
                H2U hP, hQ, lP, lQ;
                hP.h = __builtin_amdgcn_cvt_pkrtz(r0, r1);
                hQ.h = __builtin_amdgcn_cvt_pkrtz(r2, r3);
                float d0 = (r0 - (float)hP.h.x) * SCALE_F;
                float d1 = (r1 - (float)hP.h.y) * SCALE_F;
                float d2 = (r2 - (float)hQ.h.x) * SCALE_F;
                float d3 = (r3 - (float)hQ.h.y) * SCALE_F;
                lP.h = __builtin_amdgcn_cvt_pkrtz(d0, d1);
                lQ.h = __builtin_amdgcn_cvt_pkrtz(d2, d3);
                *(uint2*)(RBh + wb[q]) = make_uint2(hP.u, hQ.u);
                *(uint2*)(RBl + wb[q]) = make_uint2(lP.u, lQ.u);
            }
        }
        __syncthreads();   // ratio fully in RB

        // ---- conv2: ratio (RB) -> s (SB) ----
        {
            f32x16 H, L1, L2;
#pragma unroll
            for (int i = 0; i < 16; ++i) { H[i] = EPS; L1[i] = 0.0f; L2[i] = 0.0f; }
#pragma unroll
            for (int c = 0; c < 4; ++c) {
                half8 hB = ldfrag(RBh + rb[c]);
                half8 lB = ldfrag(RBl + rb[c]);
                H  = __builtin_amdgcn_mfma_f32_32x32x16_f16(hA[c], hB, H,  0, 0, 0);
                L1 = __builtin_amdgcn_mfma_f32_32x32x16_f16(lA[c], hB, L1, 0, 0, 0);
                L2 = __builtin_amdgcn_mfma_f32_32x32x16_f16(hA[c], lB, L2, 0, 0, 0);
            }
#pragma unroll
            for (int q = 0; q < 4; ++q) {
                float c0 = fmaxf(fmaf(L1[4*q+0] + L2[4*q+0], INV_SCALE, H[4*q+0]), EPS);
                float c1 = fmaxf(fmaf(L1[4*q+1] + L2[4*q+1], INV_SCALE, H[4*q+1]), EPS);
                float c2 = fmaxf(fmaf(L1[4*q+2] + L2[4*q+2], INV_SCALE, H[4*q+2]), EPS);
                float c3 = fmaxf(fmaf(L1[4*q+3] + L2[4*q+3], INV_SCALE, H[4*q+3]), EPS);
                if (av != 1.0f) {             // scalar (SGPR) branch
                    c0 = powf(c0, av); c1 = powf(c1, av);
                    c2 = powf(c2, av); c3 = powf(c3, av);
                }
                float s0 = fmaxf(sreg[4*q+0] * c0, EPS);
                float s1 = fmaxf(sreg[4*q+1] * c1, EPS);
                float s2 = fmaxf(sreg[4*q+2] * c2, EPS);
                float s3 = fmaxf(sreg[4*q+3] * c3, EPS);
                sreg[4*q+0] = s0; sreg[4*q+1] = s1;
                sreg[4*q+2] = s2; sreg[4*q+3] = s3;
                H2U hP, hQ, lP, lQ;
                hP.h = __builtin_amdgcn_cvt_pkrtz(s0, s1);
                hQ.h = __builtin_amdgcn_cvt_pkrtz(s2, s3);
                float d0 = (s0 - (float)hP.h.x) * SCALE_F;
                float d1 = (s1 - (float)hP.h.y) * SCALE_F;
                float d2 = (s2 - (float)hQ.h.x) * SCALE_F;
                float d3 = (s3 - (float)hQ.h.y) * SCALE_F;
                lP.h = __builtin_amdgcn_cvt_pkrtz(d0, d1);
                lQ.h = __builtin_amdgcn_cvt_pkrtz(d2, d3);
                *(uint2*)(SBh + wb[q]) = make_uint2(hP.u, hQ.u);
                *(uint2*)(SBl + wb[q]) = make_uint2(lP.u, lQ.u);
            }
        }
        __syncthreads();   // s fully in SB for next layer
    }

    // final s -> out; wave covers full 128B segments across q
#pragma unroll
    for (int q = 0; q < 4; ++q) {
        *(float4*)(orow + 32 * col + 8 * q + 4 * h) =
            make_float4(sreg[4*q+0], sreg[4*q+1], sreg[4*q+2], sreg[4*q+3]);
    }
}

extern "C" void kernel_launch(void* const* d_in, const int* in_sizes, int n_in,
                              void* d_out, int out_size, void* d_ws, size_t ws_size,
                              hipStream_t stream) {
    const float* m     = (const float*)d_in[0];
    const float* psf   = (const float*)d_in[1];
    const float* alpha = (const float*)d_in[2];
    float* out = (float*)d_out;
    const int B = in_sizes[0] / LROW;   // 4096 rows
    drl_kernel<<<dim3(B), dim3(NT), 0, stream>>>(m, psf, alpha, out);
}

// Round 7
// 451.239 us; speedup vs baseline: 1.5343x; 1.5343x over previous
//
#include <hip/hip_runtime.h>
#include <math.h>

#define EPS     1e-6f
#define LROW    8192
#define NLAYER  10
#define NT      512            // 8 waves / block, one row per block

// LDS: s and ratio each as two half-arrays (hi f16, lo f16 scaled by 2^11).
// elem e -> byte swz(2*(e+16)) inside a half-array; 16-elem zero guards both ends.
#define HBUF    16448          // (16 + 8192 + 16) * 2 bytes
#define SCALE_F   2048.0f
#define INV_SCALE 4.8828125e-4f   // 2^-11

typedef _Float16 half8  __attribute__((ext_vector_type(8)));
typedef __fp16   fp16x2 __attribute__((ext_vector_type(2)));
typedef float    f32x16 __attribute__((ext_vector_type(16)));

union H8U { uint4 u; half8 h; };
union H2U { fp16x2 h; unsigned int u; };

__device__ __forceinline__ half8 ldfrag(const char* p) {
    H8U w; w.u = *(const uint4*)(p); return w.h;
}

// XOR-swizzle: relocate each 16B slot within its 128B line by (line&7).
// For the 32x32 fragment pattern (64 distinct blocks at 64j+16h) every
// consecutive-8-lane phase hits all 8 bank-groups exactly once.
__device__ __forceinline__ int swz(int a) { return a ^ ((a >> 3) & 0x70); }

struct HL { _Float16 h, l; };
__device__ __forceinline__ HL fsplit(float v) {
    HL r;
    r.h = (_Float16)v;
    r.l = (_Float16)((v - (float)r.h) * SCALE_F);
    return r;
}

__device__ __forceinline__ float sgpr_f(float v) {
    return __int_as_float(__builtin_amdgcn_readfirstlane(__float_as_int(v)));
}

__global__ __launch_bounds__(NT, 4) void drl_kernel(
    const float* __restrict__ m,
    const float* __restrict__ psf,
    const float* __restrict__ alpha,
    float* __restrict__ out)
{
    __shared__ __align__(16) char lds[4 * HBUF + 384];
    char* SBh = lds;                 // s hi
    char* SBl = lds + HBUF;          // s lo (scaled)
    char* RBh = lds + 2 * HBUF;      // ratio hi
    char* RBl = lds + 3 * HBUF;      // ratio lo (scaled)
    float* wl2 = (float*)(lds + 4 * HBUF);   // 96-entry zero-padded taps

    const int t    = threadIdx.x;
    const int lane = t & 63;
    const int wid  = t >> 6;         // wave id 0..7
    const int aj   = lane & 31;      // A row / B col / C col
    const int h    = lane >> 5;      // k-half select
    const int col  = 32 * wid + aj;  // this lane's output group (0..255)
    const int row  = blockIdx.x;
    const float* mrow = m + (size_t)row * LROW;
    float*       orow = out + (size_t)row * LROW;

    // bulk-zero all four half-arrays (covers guards and lo arrays) + taps
    {
        const uint4 z4 = make_uint4(0u, 0u, 0u, 0u);
        uint4* z = (uint4*)lds;
#pragma unroll
        for (int k = 0; k < 9; ++k) {
            int i = t + NT * k;
            if (i < 4112) z[i] = z4;          // 4*16448/16 = 4112 blocks
        }
        if (t < 96) wl2[t] = (t >= 32 && t <= 62) ? psf[t - 32] : 0.0f;
    }
    __syncthreads();

    // s interior hi = 0.5h (16 elems per thread, two swizzled 16B stores)
    {
        const uint4 p5 = make_uint4(0x38003800u, 0x38003800u, 0x38003800u, 0x38003800u);
        int a0 = swz(32 * t + 32);
        *(uint4*)(SBh + a0) = p5;
        int a1 = swz(32 * t + 48);
        *(uint4*)(SBh + a1) = p5;
    }
    __syncthreads();

    // A-fragments for 32x32x16 f16 MFMA, 4 K-chunks, hi/lo split.
    // A_c[i][kk] = psf[16c + kk - i - 1] (zero-padded), i = aj, kk = 8h + j.
    // psf is bitwise symmetric => same fragments serve both convolutions.
    half8 hA[4], lA[4];
#pragma unroll
    for (int c = 0; c < 4; ++c) {
#pragma unroll
        for (int j = 0; j < 8; ++j) {
            HL w = fsplit(wl2[16 * c + 8 * h + j - aj + 31]);
            hA[c][j] = w.h; lA[c][j] = w.l;
        }
    }

    // swizzled byte offsets (per K-chunk reads, per reg-quad writes)
    int rb[4], wb[4];
#pragma unroll
    for (int c = 0; c < 4; ++c) {
        rb[c] = swz(64 * col + 32 * c + 16 * h);       // B frag: elem 32col-16+16c+8h
        wb[c] = swz(64 * col + 16 * c + 8 * h + 32);   // C quad: elem 32col+8c+4h
    }

    float sreg[16];
#pragma unroll
    for (int i = 0; i < 16; ++i) sreg[i] = 0.5f;

#pragma unroll 1
    for (int layer = 0; layer < NLAYER; ++layer) {
        const float av = sgpr_f(alpha[layer]);

        // ---- conv1: s (SB) -> ratio (RB) ----
        {
            f32x16 H, L;
#pragma unroll
            for (int i = 0; i < 16; ++i) { H[i] = EPS; L[i] = 0.0f; }
#pragma unroll
            for (int c = 0; c < 4; ++c) {
                half8 hB = ldfrag(SBh + rb[c]);
                half8 lB = ldfrag(SBl + rb[c]);
                H = __builtin_amdgcn_mfma_f32_32x32x16_f16(hA[c], hB, H, 0, 0, 0);
                L = __builtin_amdgcn_mfma_f32_32x32x16_f16(lA[c], hB, L, 0, 0, 0);
                L = __builtin_amdgcn_mfma_f32_32x32x16_f16(hA[c], lB, L, 0, 0, 0);
            }
            // x re-loaded per layer (L2-resident: 32 KB/row reused 10x) — frees
            // 16 persistent VGPRs vs keeping xr[] across the whole kernel.
#pragma unroll
            for (int q = 0; q < 4; ++q) {
                float4 xv = *(const float4*)(mrow + 32 * col + 8 * q + 4 * h);
                float a0 = fmaf(L[4*q+0], INV_SCALE, H[4*q+0]);
                float a1 = fmaf(L[4*q+1], INV_SCALE, H[4*q+1]);
                float a2 = fmaf(L[4*q+2], INV_SCALE, H[4*q+2]);
                float a3 = fmaf(L[4*q+3], INV_SCALE, H[4*q+3]);
                float r0 = xv.x * __builtin_amdgcn_rcpf(a0);
                float r1 = xv.y * __builtin_amdgcn_rcpf(a1);
                float r2 = xv.z * __builtin_amdgcn_rcpf(a2);
                float r3 = xv.w * __builtin_amdgcn_rcpf(a3);
                H2U hP, hQ, lP, lQ;
                hP.h = __builtin_amdgcn_cvt_pkrtz(r0, r1);
                hQ.h = __builtin_amdgcn_cvt_pkrtz(r2, r3);
                float d0 = (r0 - (float)hP.h.x) * SCALE_F;
                float d1 = (r1 - (float)hP.h.y) * SCALE_F;
                float d2 = (r2 - (float)hQ.h.x) * SCALE_F;
                float d3 = (r3 - (float)hQ.h.y) * SCALE_F;
                lP.h = __builtin_amdgcn_cvt_pkrtz(d0, d1);
                lQ.h = __builtin_amdgcn_cvt_pkrtz(d2, d3);
                *(uint2*)(RBh + wb[q]) = make_uint2(hP.u, hQ.u);
                *(uint2*)(RBl + wb[q]) = make_uint2(lP.u, lQ.u);
            }
        }
        __syncthreads();   // ratio fully in RB

        // ---- conv2: ratio (RB) -> s (SB) ----
        {
            f32x16 H, L;
#pragma unroll
            for (int i = 0; i < 16; ++i) { H[i] = EPS; L[i] = 0.0f; }
#pragma unroll
            for (int c = 0; c < 4; ++c) {
                half8 hB = ldfrag(RBh + rb[c]);
                half8 lB = ldfrag(RBl + rb[c]);
                H = __builtin_amdgcn_mfma_f32_32x32x16_f16(hA[c], hB, H, 0, 0, 0);
                L = __builtin_amdgcn_mfma_f32_32x32x16_f16(lA[c], hB, L, 0, 0, 0);
                L = __builtin_amdgcn_mfma_f32_32x32x16_f16(hA[c], lB, L, 0, 0, 0);
            }
#pragma unroll
            for (int q = 0; q < 4; ++q) {
                float c0 = fmaxf(fmaf(L[4*q+0], INV_SCALE, H[4*q+0]), EPS);
                float c1 = fmaxf(fmaf(L[4*q+1], INV_SCALE, H[4*q+1]), EPS);
                float c2 = fmaxf(fmaf(L[4*q+2], INV_SCALE, H[4*q+2]), EPS);
                float c3 = fmaxf(fmaf(L[4*q+3], INV_SCALE, H[4*q+3]), EPS);
                if (av != 1.0f) {             // scalar (SGPR) branch
                    c0 = powf(c0, av); c1 = powf(c1, av);
                    c2 = powf(c2, av); c3 = powf(c3, av);
                }
                float s0 = fmaxf(sreg[4*q+0] * c0, EPS);
                float s1 = fmaxf(sreg[4*q+1] * c1, EPS);
                float s2 = fmaxf(sreg[4*q+2] * c2, EPS);
                float s3 = fmaxf(sreg[4*q+3] * c3, EPS);
                sreg[4*q+0] = s0; sreg[4*q+1] = s1;
                sreg[4*q+2] = s2; sreg[4*q+3] = s3;
                H2U hP, hQ, lP, lQ;
                hP.h = __builtin_amdgcn_cvt_pkrtz(s0, s1);
                hQ.h = __builtin_amdgcn_cvt_pkrtz(s2, s3);
                float d0 = (s0 - (float)hP.h.x) * SCALE_F;
                float d1 = (s1 - (float)hP.h.y) * SCALE_F;
                float d2 = (s2 - (float)hQ.h.x) * SCALE_F;
                float d3 = (s3 - (float)hQ.h.y) * SCALE_F;
                lP.h = __builtin_amdgcn_cvt_pkrtz(d0, d1);
                lQ.h = __builtin_amdgcn_cvt_pkrtz(d2, d3);
                *(uint2*)(SBh + wb[q]) = make_uint2(hP.u, hQ.u);
                *(uint2*)(SBl + wb[q]) = make_uint2(lP.u, lQ.u);
            }
        }
        __syncthreads();   // s fully in SB for next layer
    }

    // final s -> out; wave covers full 128B segments across q
#pragma unroll
    for (int q = 0; q < 4; ++q) {
        *(float4*)(orow + 32 * col + 8 * q + 4 * h) =
            make_float4(sreg[4*q+0], sreg[4*q+1], sreg[4*q+2], sreg[4*q+3]);
    }
}

extern "C" void kernel_launch(void* const* d_in, const int* in_sizes, int n_in,
                              void* d_out, int out_size, void* d_ws, size_t ws_size,
                              hipStream_t stream) {
    const float* m     = (const float*)d_in[0];
    const float* psf   = (const float*)d_in[1];
    const float* alpha = (const float*)d_in[2];
    float* out = (float*)d_out;
    const int B = in_sizes[0] / LROW;   // 4096 rows
    drl_kernel<<<dim3(B), dim3(NT), 0, stream>>>(m, psf, alpha, out);
}

// Round 8
// 400.764 us; speedup vs baseline: 1.7275x; 1.1259x over previous
//
#include <hip/hip_runtime.h>
#include <math.h>

#define EPS     1e-6f
#define LROW    8192
#define NLAYER  10
#define NT      512            // 8 waves / block, one row per block

// LDS: s and ratio each as two half-arrays (hi f16, lo f16 UNSCALED).
// elem e -> byte swz(2*(e+16)) inside a half-array; 16-elem zero guards both ends.
#define HBUF    16448          // (16 + 8192 + 16) * 2 bytes

typedef _Float16 half8  __attribute__((ext_vector_type(8)));
typedef __fp16   fp16x2 __attribute__((ext_vector_type(2)));
typedef float    f32x16 __attribute__((ext_vector_type(16)));

union H8U { uint4 u; half8 h; };
union H2U { fp16x2 h; unsigned int u; };

__device__ __forceinline__ half8 ldfrag(const char* p) {
    H8U w; w.u = *(const uint4*)(p); return w.h;
}

// XOR-swizzle: relocate each 16B slot within its 128B line by (line&7).
// For the 32x32 fragment pattern (64 distinct blocks at 64j+16h) every
// consecutive-8-lane phase hits all 8 bank-groups exactly once.
__device__ __forceinline__ int swz(int a) { return a ^ ((a >> 3) & 0x70); }

// hi/lo split, lo UNSCALED: v ~= hi + lo with |lo| <= 2^-11 |v|.
// Cross terms then share the hi*hi scale -> single MFMA accumulator.
struct HL { _Float16 h, l; };
__device__ __forceinline__ HL fsplit(float v) {
    HL r;
    r.h = (_Float16)v;
    r.l = (_Float16)(v - (float)r.h);
    return r;
}

__device__ __forceinline__ float sgpr_f(float v) {
    return __int_as_float(__builtin_amdgcn_readfirstlane(__float_as_int(v)));
}

__global__ __launch_bounds__(NT, 4) void drl_kernel(
    const float* __restrict__ m,
    const float* __restrict__ psf,
    const float* __restrict__ alpha,
    float* __restrict__ out)
{
    __shared__ __align__(16) char lds[4 * HBUF + 384];
    char* SBh = lds;                 // s hi
    char* SBl = lds + HBUF;          // s lo
    char* RBh = lds + 2 * HBUF;      // ratio hi
    char* RBl = lds + 3 * HBUF;      // ratio lo
    float* wl2 = (float*)(lds + 4 * HBUF);   // 96-entry zero-padded taps

    const int t    = threadIdx.x;
    const int lane = t & 63;
    const int wid  = t >> 6;         // wave id 0..7
    const int aj   = lane & 31;      // A row / B col / C col
    const int h    = lane >> 5;      // k-half select
    const int col  = 32 * wid + aj;  // this lane's output group (0..255)
    const int row  = blockIdx.x;
    const float* mrow = m + (size_t)row * LROW;
    float*       orow = out + (size_t)row * LROW;

    // bulk-zero all four half-arrays (covers guards and lo arrays) + taps
    {
        const uint4 z4 = make_uint4(0u, 0u, 0u, 0u);
        uint4* z = (uint4*)lds;
#pragma unroll
        for (int k = 0; k < 9; ++k) {
            int i = t + NT * k;
            if (i < 4112) z[i] = z4;          // 4*16448/16 = 4112 blocks
        }
        if (t < 96) wl2[t] = (t >= 32 && t <= 62) ? psf[t - 32] : 0.0f;
    }
    __syncthreads();

    // s interior hi = 0.5h (16 elems per thread, two swizzled 16B stores)
    {
        const uint4 p5 = make_uint4(0x38003800u, 0x38003800u, 0x38003800u, 0x38003800u);
        int a0 = swz(32 * t + 32);
        *(uint4*)(SBh + a0) = p5;
        int a1 = swz(32 * t + 48);
        *(uint4*)(SBh + a1) = p5;
    }
    __syncthreads();

    // A-fragments for 32x32x16 f16 MFMA, 4 K-chunks, hi/lo split.
    // A_c[i][kk] = psf[16c + kk - i - 1] (zero-padded), i = aj, kk = 8h + j.
    // psf is bitwise symmetric => same fragments serve both convolutions.
    half8 hA[4], lA[4];
#pragma unroll
    for (int c = 0; c < 4; ++c) {
#pragma unroll
        for (int j = 0; j < 8; ++j) {
            HL w = fsplit(wl2[16 * c + 8 * h + j - aj + 31]);
            hA[c][j] = w.h; lA[c][j] = w.l;
        }
    }

    // swizzled byte offsets (per K-chunk reads, per reg-quad writes)
    int rb[4], wb[4];
#pragma unroll
    for (int c = 0; c < 4; ++c) {
        rb[c] = swz(64 * col + 32 * c + 16 * h);       // B frag: elem 32col-16+16c+8h
        wb[c] = swz(64 * col + 16 * c + 8 * h + 32);   // C quad: elem 32col+8c+4h
    }

    float sreg[16];
#pragma unroll
    for (int i = 0; i < 16; ++i) sreg[i] = 0.5f;

#pragma unroll 1
    for (int layer = 0; layer < NLAYER; ++layer) {
        const float av = sgpr_f(alpha[layer]);

        // ---- conv1: s (SB) -> ratio (RB) ----
        {
            f32x16 C;
#pragma unroll
            for (int i = 0; i < 16; ++i) C[i] = EPS;
#pragma unroll
            for (int c = 0; c < 4; ++c) {
                half8 hB = ldfrag(SBh + rb[c]);
                half8 lB = ldfrag(SBl + rb[c]);
                C = __builtin_amdgcn_mfma_f32_32x32x16_f16(hA[c], hB, C, 0, 0, 0);
                C = __builtin_amdgcn_mfma_f32_32x32x16_f16(lA[c], hB, C, 0, 0, 0);
                C = __builtin_amdgcn_mfma_f32_32x32x16_f16(hA[c], lB, C, 0, 0, 0);
            }
            // x re-loaded per layer (L2-resident: 32 KB/row reused 10x) — frees
            // 16 persistent VGPRs vs keeping xr[] across the whole kernel.
#pragma unroll
            for (int q = 0; q < 4; ++q) {
                float4 xv = *(const float4*)(mrow + 32 * col + 8 * q + 4 * h);
                float r0 = xv.x * __builtin_amdgcn_rcpf(C[4*q+0]);
                float r1 = xv.y * __builtin_amdgcn_rcpf(C[4*q+1]);
                float r2 = xv.z * __builtin_amdgcn_rcpf(C[4*q+2]);
                float r3 = xv.w * __builtin_amdgcn_rcpf(C[4*q+3]);
                H2U hP, hQ, lP, lQ;
                hP.h = __builtin_amdgcn_cvt_pkrtz(r0, r1);
                hQ.h = __builtin_amdgcn_cvt_pkrtz(r2, r3);
                float d0 = r0 - (float)hP.h.x;
                float d1 = r1 - (float)hP.h.y;
                float d2 = r2 - (float)hQ.h.x;
                float d3 = r3 - (float)hQ.h.y;
                lP.h = __builtin_amdgcn_cvt_pkrtz(d0, d1);
                lQ.h = __builtin_amdgcn_cvt_pkrtz(d2, d3);
                *(uint2*)(RBh + wb[q]) = make_uint2(hP.u, hQ.u);
                *(uint2*)(RBl + wb[q]) = make_uint2(lP.u, lQ.u);
            }
        }
        __syncthreads();   // ratio fully in RB

        // ---- conv2: ratio (RB) -> s (SB) ----
        {
            f32x16 C;
#pragma unroll
            for (int i = 0; i < 16; ++i) C[i] = EPS;
#pragma unroll
            for (int c = 0; c < 4; ++c) {
                half8 hB = ldfrag(RBh + rb[c]);
                half8 lB = ldfrag(RBl + rb[c]);
                C = __builtin_amdgcn_mfma_f32_32x32x16_f16(hA[c], hB, C, 0, 0, 0);
                C = __builtin_amdgcn_mfma_f32_32x32x16_f16(lA[c], hB, C, 0, 0, 0);
                C = __builtin_amdgcn_mfma_f32_32x32x16_f16(hA[c], lB, C, 0, 0, 0);
            }
#pragma unroll
            for (int q = 0; q < 4; ++q) {
                float c0 = fmaxf(C[4*q+0], EPS);
                float c1 = fmaxf(C[4*q+1], EPS);
                float c2 = fmaxf(C[4*q+2], EPS);
                float c3 = fmaxf(C[4*q+3], EPS);
                if (av != 1.0f) {             // scalar (SGPR) branch
                    c0 = powf(c0, av); c1 = powf(c1, av);
                    c2 = powf(c2, av); c3 = powf(c3, av);
                }
                float s0 = fmaxf(sreg[4*q+0] * c0, EPS);
                float s1 = fmaxf(sreg[4*q+1] * c1, EPS);
                float s2 = fmaxf(sreg[4*q+2] * c2, EPS);
                float s3 = fmaxf(sreg[4*q+3] * c3, EPS);
                sreg[4*q+0] = s0; sreg[4*q+1] = s1;
                sreg[4*q+2] = s2; sreg[4*q+3] = s3;
                H2U hP, hQ, lP, lQ;
                hP.h = __builtin_amdgcn_cvt_pkrtz(s0, s1);
                hQ.h = __builtin_amdgcn_cvt_pkrtz(s2, s3);
                float d0 = s0 - (float)hP.h.x;
                float d1 = s1 - (float)hP.h.y;
                float d2 = s2 - (float)hQ.h.x;
                float d3 = s3 - (float)hQ.h.y;
                lP.h = __builtin_amdgcn_cvt_pkrtz(d0, d1);
                lQ.h = __builtin_amdgcn_cvt_pkrtz(d2, d3);
                *(uint2*)(SBh + wb[q]) = make_uint2(hP.u, hQ.u);
                *(uint2*)(SBl + wb[q]) = make_uint2(lP.u, lQ.u);
            }
        }
        __syncthreads();   // s fully in SB for next layer
    }

    // final s -> out; wave covers full 128B segments across q
#pragma unroll
    for (int q = 0; q < 4; ++q) {
        *(float4*)(orow + 32 * col + 8 * q + 4 * h) =
            make_float4(sreg[4*q+0], sreg[4*q+1], sreg[4*q+2], sreg[4*q+3]);
    }
}

extern "C" void kernel_launch(void* const* d_in, const int* in_sizes, int n_in,
                              void* d_out, int out_size, void* d_ws, size_t ws_size,
                              hipStream_t stream) {
    const float* m     = (const float*)d_in[0];
    const float* psf   = (const float*)d_in[1];
    const float* alpha = (const float*)d_in[2];
    float* out = (float*)d_out;
    const int B = in_sizes[0] / LROW;   // 4096 rows
    drl_kernel<<<dim3(B), dim3(NT), 0, stream>>>(m, psf, alpha, out);
}

// Round 9
// 399.980 us; speedup vs baseline: 1.7309x; 1.0020x over previous
//
#include <hip/hip_runtime.h>
#include <math.h>

#define EPS     1e-6f
#define LROW    8192
#define NLAYER  10
#define NT      512            // 8 waves / block, one row per block

// LDS: s and ratio each as two half-arrays (hi f16, lo f16 UNSCALED).
// elem e -> block v=(e+16)>>3 placed at blkaddr(v); 16-elem zero guards both ends.
// 1028 data blocks padded to 1056 (33 groups of 32) for the rotation layout.
#define HBUF    16896          // 1056 blocks * 16 B

typedef _Float16 half8  __attribute__((ext_vector_type(8)));
typedef __fp16   fp16x2 __attribute__((ext_vector_type(2)));
typedef float    f32x16 __attribute__((ext_vector_type(16)));

union H8U { uint4 u; half8 h; };
union H2U { fp16x2 h; unsigned int u; };

__device__ __forceinline__ half8 ldfrag(const char* p) {
    H8U w; w.u = *(const uint4*)(p); return w.h;
}

// Rotation layout: block v -> 16B slot at byte 16*pi(v), where pi rotates the
// 5-bit within-group index right by 2:  pi(v) = (v&~31)|((v&3)<<3)|((v>>2)&7).
// Slot-mod-8 = bits 2-4 of v, so any stride-4 8-lane phase {B+4k} hits
// ((B>>2)+k) mod 8 = all 8 bank-groups exactly once, for EVERY B (the XOR
// swizzle failed this when B&7>=4: key increment mid-phase collided lanes 0,7).
__device__ __forceinline__ int blkaddr(int v) {
    return ((v & ~31) | ((v & 3) << 3) | ((v >> 2) & 7)) << 4;
}

// hi/lo split, lo UNSCALED: v ~= hi + lo with |lo| <= 2^-11 |v|.
// Cross terms share the hi*hi scale -> single MFMA accumulator.
struct HL { _Float16 h, l; };
__device__ __forceinline__ HL fsplit(float v) {
    HL r;
    r.h = (_Float16)v;
    r.l = (_Float16)(v - (float)r.h);
    return r;
}

__device__ __forceinline__ float sgpr_f(float v) {
    return __int_as_float(__builtin_amdgcn_readfirstlane(__float_as_int(v)));
}

__global__ __launch_bounds__(NT, 4) void drl_kernel(
    const float* __restrict__ m,
    const float* __restrict__ psf,
    const float* __restrict__ alpha,
    float* __restrict__ out)
{
    __shared__ __align__(16) char lds[4 * HBUF + 384];
    char* SBh = lds;                 // s hi
    char* SBl = lds + HBUF;          // s lo
    char* RBh = lds + 2 * HBUF;      // ratio hi
    char* RBl = lds + 3 * HBUF;      // ratio lo
    float* wl2 = (float*)(lds + 4 * HBUF);   // 96-entry zero-padded taps

    const int t    = threadIdx.x;
    const int lane = t & 63;
    const int wid  = t >> 6;         // wave id 0..7
    const int aj   = lane & 31;      // A row / B col / C col
    const int h    = lane >> 5;      // k-half select
    const int col  = 32 * wid + aj;  // this lane's output group (0..255)
    const int row  = blockIdx.x;
    const float* mrow = m + (size_t)row * LROW;
    float*       orow = out + (size_t)row * LROW;

    // bulk-zero all four half-arrays (guards, pads, lo arrays) + taps
    {
        const uint4 z4 = make_uint4(0u, 0u, 0u, 0u);
        uint4* z = (uint4*)lds;
#pragma unroll
        for (int k = 0; k < 9; ++k) {
            int i = t + NT * k;
            if (i < 4224) z[i] = z4;          // 4*16896/16 = 4224 blocks
        }
        if (t < 96) wl2[t] = (t >= 32 && t <= 62) ? psf[t - 32] : 0.0f;
    }
    __syncthreads();

    // s interior hi = 0.5h: thread t owns elems [16t,16t+16) -> blocks 2t+2, 2t+3
    {
        const uint4 p5 = make_uint4(0x38003800u, 0x38003800u, 0x38003800u, 0x38003800u);
        *(uint4*)(SBh + blkaddr(2 * t + 2)) = p5;
        *(uint4*)(SBh + blkaddr(2 * t + 3)) = p5;
    }
    __syncthreads();

    // A-fragments for 32x32x16 f16 MFMA, 4 K-chunks, hi/lo split.
    // A_c[i][kk] = psf[16c + kk - i - 1] (zero-padded), i = aj, kk = 8h + j.
    // psf is bitwise symmetric => same fragments serve both convolutions.
    half8 hA[4], lA[4];
#pragma unroll
    for (int c = 0; c < 4; ++c) {
#pragma unroll
        for (int j = 0; j < 8; ++j) {
            HL w = fsplit(wl2[16 * c + 8 * h + j - aj + 31]);
            hA[c][j] = w.h; lA[c][j] = w.l;
        }
    }

    // byte offsets (per K-chunk fragment reads, per reg-quad writes)
    // B frag chunk c: elems 32col-16+16c+8h.. +8  -> block 4col+2c+h
    // C quad q:      elems 32col+8q+4h.. +4       -> block 4col+q+2, byte +8h
    int rb[4], wb[4];
#pragma unroll
    for (int c = 0; c < 4; ++c) {
        rb[c] = blkaddr(4 * col + 2 * c + h);
        wb[c] = blkaddr(4 * col + c + 2) + 8 * h;
    }

    float sreg[16];
#pragma unroll
    for (int i = 0; i < 16; ++i) sreg[i] = 0.5f;

#pragma unroll 1
    for (int layer = 0; layer < NLAYER; ++layer) {
        const float av = sgpr_f(alpha[layer]);

        // ---- conv1: s (SB) -> ratio (RB) ----
        {
            f32x16 C;
#pragma unroll
            for (int i = 0; i < 16; ++i) C[i] = EPS;
#pragma unroll
            for (int c = 0; c < 4; ++c) {
                half8 hB = ldfrag(SBh + rb[c]);
                half8 lB = ldfrag(SBl + rb[c]);
                C = __builtin_amdgcn_mfma_f32_32x32x16_f16(hA[c], hB, C, 0, 0, 0);
                C = __builtin_amdgcn_mfma_f32_32x32x16_f16(lA[c], hB, C, 0, 0, 0);
                C = __builtin_amdgcn_mfma_f32_32x32x16_f16(hA[c], lB, C, 0, 0, 0);
            }
            // x re-loaded per layer (L2-resident: 32 KB/row reused 10x) — frees
            // 16 persistent VGPRs vs keeping xr[] across the whole kernel.
#pragma unroll
            for (int q = 0; q < 4; ++q) {
                float4 xv = *(const float4*)(mrow + 32 * col + 8 * q + 4 * h);
                float r0 = xv.x * __builtin_amdgcn_rcpf(C[4*q+0]);
                float r1 = xv.y * __builtin_amdgcn_rcpf(C[4*q+1]);
                float r2 = xv.z * __builtin_amdgcn_rcpf(C[4*q+2]);
                float r3 = xv.w * __builtin_amdgcn_rcpf(C[4*q+3]);
                H2U hP, hQ, lP, lQ;
                hP.h = __builtin_amdgcn_cvt_pkrtz(r0, r1);
                hQ.h = __builtin_amdgcn_cvt_pkrtz(r2, r3);
                float d0 = r0 - (float)hP.h.x;
                float d1 = r1 - (float)hP.h.y;
                float d2 = r2 - (float)hQ.h.x;
                float d3 = r3 - (float)hQ.h.y;
                lP.h = __builtin_amdgcn_cvt_pkrtz(d0, d1);
                lQ.h = __builtin_amdgcn_cvt_pkrtz(d2, d3);
                *(uint2*)(RBh + wb[q]) = make_uint2(hP.u, hQ.u);
                *(uint2*)(RBl + wb[q]) = make_uint2(lP.u, lQ.u);
            }
        }
        __syncthreads();   // ratio fully in RB

        // ---- conv2: ratio (RB) -> s (SB) ----
        {
            f32x16 C;
#pragma unroll
            for (int i = 0; i < 16; ++i) C[i] = EPS;
#pragma unroll
            for (int c = 0; c < 4; ++c) {
                half8 hB = ldfrag(RBh + rb[c]);
                half8 lB = ldfrag(RBl + rb[c]);
                C = __builtin_amdgcn_mfma_f32_32x32x16_f16(hA[c], hB, C, 0, 0, 0);
                C = __builtin_amdgcn_mfma_f32_32x32x16_f16(lA[c], hB, C, 0, 0, 0);
                C = __builtin_amdgcn_mfma_f32_32x32x16_f16(hA[c], lB, C, 0, 0, 0);
            }
#pragma unroll
            for (int q = 0; q < 4; ++q) {
                float c0 = fmaxf(C[4*q+0], EPS);
                float c1 = fmaxf(C[4*q+1], EPS);
                float c2 = fmaxf(C[4*q+2], EPS);
                float c3 = fmaxf(C[4*q+3], EPS);
                if (av != 1.0f) {             // scalar (SGPR) branch
                    c0 = powf(c0, av); c1 = powf(c1, av);
                    c2 = powf(c2, av); c3 = powf(c3, av);
                }
                float s0 = fmaxf(sreg[4*q+0] * c0, EPS);
                float s1 = fmaxf(sreg[4*q+1] * c1, EPS);
                float s2 = fmaxf(sreg[4*q+2] * c2, EPS);
                float s3 = fmaxf(sreg[4*q+3] * c3, EPS);
                sreg[4*q+0] = s0; sreg[4*q+1] = s1;
                sreg[4*q+2] = s2; sreg[4*q+3] = s3;
                H2U hP, hQ, lP, lQ;
                hP.h = __builtin_amdgcn_cvt_pkrtz(s0, s1);
                hQ.h = __builtin_amdgcn_cvt_pkrtz(s2, s3);
                float d0 = s0 - (float)hP.h.x;
                float d1 = s1 - (float)hP.h.y;
                float d2 = s2 - (float)hQ.h.x;
                float d3 = s3 - (float)hQ.h.y;
                lP.h = __builtin_amdgcn_cvt_pkrtz(d0, d1);
                lQ.h = __builtin_amdgcn_cvt_pkrtz(d2, d3);
                *(uint2*)(SBh + wb[q]) = make_uint2(hP.u, hQ.u);
                *(uint2*)(SBl + wb[q]) = make_uint2(lP.u, lQ.u);
            }
        }
        __syncthreads();   // s fully in SB for next layer
    }

    // final s -> out; wave covers full 128B segments across q
#pragma unroll
    for (int q = 0; q < 4; ++q) {
        *(float4*)(orow + 32 * col + 8 * q + 4 * h) =
            make_float4(sreg[4*q+0], sreg[4*q+1], sreg[4*q+2], sreg[4*q+3]);
    }
}

extern "C" void kernel_launch(void* const* d_in, const int* in_sizes, int n_in,
                              void* d_out, int out_size, void* d_ws, size_t ws_size,
                              hipStream_t stream) {
    const float* m     = (const float*)d_in[0];
    const float* psf   = (const float*)d_in[1];
    const float* alpha = (const float*)d_in[2];
    float* out = (float*)d_out;
    const int B = in_sizes[0] / LROW;   // 4096 rows
    drl_kernel<<<dim3(B), dim3(NT), 0, stream>>>(m, psf, alpha, out);
}